// Round 3
// baseline (939.643 us; speedup 1.0000x reference)
//
#include <hip/hip_runtime.h>

// ---------------- constants ----------------
#define B_    64
#define CIN   64
#define CH    256
#define T_    2048
#define NP    10
#define INVLN2 1.44269504088896340736f
#define INFV  1e10f
#define TPAD  2064   // 2048 rows + 16 dump rows for DP boundary spill

// d_out element offsets (float32)
static const size_t DO_H   = 0;
static const size_t DO_OUT = 33554432;
static const size_t DO_ENS = 33555072;
static const size_t DO_ONE = 34046592;
static const size_t DO_OP  = 34210432;
static const size_t DO_ATT = 34210433;

// d_ws element offsets (float32)
static const size_t OFF_D2 = 0;         // [64][2064][16]
static const size_t OFF_Y  = 2113536;   // [64][2064][16]
static const size_t OFF_A  = 4227072;   // [64][2064][16]
static const size_t OFF_RS = 6340608;   // [64][16]
static const size_t OFF_O1 = 6341632;   // [64][256]
static const size_t OFF_O2 = 6358016;   // [64][256][10]  (memset from here: k1 atomically accumulates raw segment sums)
static const size_t OFF_O3 = 6521856;   // [64][256][10]
static const size_t OFF_IND= 6685696;   // [0]=ind sum, [1]=op float
static const size_t OFF_Z1 = 6685712;   // [64][512]
static const size_t OFF_Z2 = 6718480;   // [64][1024]
static const size_t WS_END = 6784016;

// lane i <- lane i-1 within 16-lane row; invalid lanes get INFV (old operand, bound_ctrl=0)
__device__ __forceinline__ float dpp_shr1_inf(float x) {
  return __int_as_float(__builtin_amdgcn_update_dpp(
      __float_as_int(INFV), __float_as_int(x), 0x111, 0xf, 0xf, false));
}
// lane i <- lane i-1 within 16-lane row; invalid lanes get 0
__device__ __forceinline__ float dpp_shr1_z(float x) {
  return __int_as_float(__builtin_amdgcn_update_dpp(0, __float_as_int(x), 0x111, 0xf, 0xf, true));
}
// lane i <- lane i+1 within 16-lane row; invalid lanes get 0
__device__ __forceinline__ float dpp_shl1_z(float x) {
  return __int_as_float(__builtin_amdgcn_update_dpp(0, __float_as_int(x), 0x101, 0xf, 0xf, true));
}

// ---------------- K1: h = relu(conv_w @ x + b), fused raw segment sums (STP) ----------------
__global__ __launch_bounds__(256) void k1_conv(const float* __restrict__ x, const float* __restrict__ w,
                                               const float* __restrict__ bias, float* __restrict__ h,
                                               float* __restrict__ out2w) {
  const int tt = blockIdx.x, ot = blockIdx.y, b = blockIdx.z;
  const int tid = threadIdx.x;
  __shared__ float xs[64][132];
  __shared__ float wt[64][64];   // transposed [c][o]
  const int t0 = tt * 128, o0 = ot * 64;
  {
    const float* xb = x + ((size_t)b * CIN) * T_ + t0;
#pragma unroll
    for (int k = 0; k < 8; ++k) {
      int idx = tid + k * 256;           // float4 index over 64x128
      int c = idx >> 5, q = idx & 31;
      float4 v = *(const float4*)(xb + (size_t)c * T_ + q * 4);
      *(float4*)(&xs[c][q * 4]) = v;
    }
#pragma unroll
    for (int k = 0; k < 4; ++k) {
      int idx = tid + k * 256;           // float4 index over 64x64
      int o = idx >> 4, c4 = (idx & 15) * 4;
      float4 v = *(const float4*)(w + (size_t)(o0 + o) * 64 + c4);
      wt[c4 + 0][o] = v.x; wt[c4 + 1][o] = v.y; wt[c4 + 2][o] = v.z; wt[c4 + 3][o] = v.w;
    }
  }
  __syncthreads();
  const int og = tid >> 4, tg = tid & 15;
  float acc[4][8];
#pragma unroll
  for (int i = 0; i < 4; ++i)
#pragma unroll
    for (int j = 0; j < 8; ++j) acc[i][j] = 0.f;
  for (int c = 0; c < 64; ++c) {
    float a0 = wt[c][og * 4 + 0], a1 = wt[c][og * 4 + 1], a2 = wt[c][og * 4 + 2], a3 = wt[c][og * 4 + 3];
    float xv[8];
#pragma unroll
    for (int j = 0; j < 8; ++j) xv[j] = xs[c][tg * 8 + j];
#pragma unroll
    for (int j = 0; j < 8; ++j) {
      acc[0][j] += a0 * xv[j]; acc[1][j] += a1 * xv[j];
      acc[2][j] += a2 * xv[j]; acc[3][j] += a3 * xv[j];
    }
  }
  // segment geometry for this thread's 8 consecutive t's
  const int tb = t0 + tg * 8;
  int s_lo = tb / 204; if (s_lo > 9) s_lo = 9;
  int s_hi = (tb + 7) / 204; if (s_hi > 9) s_hi = 9;
  const int cross = (s_hi > s_lo) ? ((s_lo + 1) * 204 - tb) : 8;

  float* hb = h + ((size_t)b * CH + o0) * T_ + t0;
#pragma unroll
  for (int i = 0; i < 4; ++i) {
    const float bv = bias[o0 + og * 4 + i];
    float vs[8];
#pragma unroll
    for (int j = 0; j < 8; ++j) vs[j] = fmaxf(acc[i][j] + bv, 0.f);
    float4 v0, v1;
    v0.x = vs[0]; v0.y = vs[1]; v0.z = vs[2]; v0.w = vs[3];
    v1.x = vs[4]; v1.y = vs[5]; v1.z = vs[6]; v1.w = vs[7];
    *(float4*)(&hb[(size_t)(og * 4 + i) * T_ + tg * 8]) = v0;
    *(float4*)(&hb[(size_t)(og * 4 + i) * T_ + tg * 8 + 4]) = v1;
    // fused STP raw segment sums
    float sumA = 0.f, sumB = 0.f;
#pragma unroll
    for (int j = 0; j < 8; ++j) { if (j < cross) sumA += vs[j]; else sumB += vs[j]; }
    float* o2p = out2w + ((size_t)(b * CH + o0 + og * 4 + i)) * NP;
    atomicAdd(o2p + s_lo, sumA);
    if (s_hi > s_lo) atomicAdd(o2p + s_hi, sumB);
  }
}

// ---------------- K2: D2[b][t][p] = (pn[p] + hn[t] - 2*PH[p,t]) / ln2 ----------------
__global__ __launch_bounds__(256) void k2_d2(const float* __restrict__ h, const float* __restrict__ protos,
                                             float* __restrict__ D2g) {
  const int tt = blockIdx.x, b = blockIdx.y, tid = threadIdx.x;
  __shared__ float pl[2560];
  __shared__ float pn[NP];
#pragma unroll
  for (int k = 0; k < 10; ++k) pl[tid + k * 256] = protos[tid + k * 256];
  __syncthreads();
  if (tid < NP) {
    float s = 0.f;
    for (int c = 0; c < CH; ++c) { float v = pl[c * NP + tid]; s += v * v; }
    pn[tid] = s;
  }
  __syncthreads();
  const int t = tt * 256 + tid;
  const float* hb = h + (size_t)b * CH * T_ + t;
  float hn = 0.f, ph[NP];
#pragma unroll
  for (int p = 0; p < NP; ++p) ph[p] = 0.f;
  for (int c = 0; c < CH; ++c) {
    float hv = hb[(size_t)c * T_];
    hn += hv * hv;
#pragma unroll
    for (int p = 0; p < NP; ++p) ph[p] += pl[c * NP + p] * hv;
  }
  float dv[16];
#pragma unroll
  for (int p = 0; p < NP; ++p) dv[p] = (pn[p] + hn - 2.f * ph[p]) * INVLN2;
#pragma unroll
  for (int p = NP; p < 16; ++p) dv[p] = 0.f;
  float* dst = D2g + ((size_t)b * TPAD + t) * 16;
#pragma unroll
  for (int q = 0; q < 4; ++q) {
    float4 v; v.x = dv[q*4]; v.y = dv[q*4+1]; v.z = dv[q*4+2]; v.w = dv[q*4+3];
    *(float4*)(dst + q * 4) = v;
  }
}

// ---------------- K3b: finalize means (out1 from raw segment sums) ----------------
__global__ __launch_bounds__(256) void k3b_fin(float* __restrict__ out2w, float* __restrict__ out1w) {
  const int b = blockIdx.x, o = threadIdx.x;
  float* p = out2w + ((size_t)(b * CH + o)) * NP;
  float vals[NP], tot = 0.f;
#pragma unroll
  for (int s = 0; s < NP; ++s) { vals[s] = p[s]; tot += vals[s]; }
  out1w[b * CH + o] = tot * (1.f / 2048.f);
#pragma unroll
  for (int s = 0; s < 9; ++s) p[s] = vals[s] * (1.f / 204.f);
  p[9] = vals[9] * (1.f / 212.f);
}

// ---------------- K4: soft-DTW forward + backward, short-chain (m,e) formulation ----------------
// One wave per batch; lanes 0-15 active (lane l = prototype row p=l, l>=10 carries benign junk).
// Cell value y = m - log2(e), e in [1,9]. Forward chain is only dpp->min3->add; exp2/log2 off-chain.
// Element offset of cell (p=l, t) in a [TPAD][16] buffer: 16*t + l = 16*d - 15*l, d = t + l.
__global__ __launch_bounds__(64) void k4_dp(const float* __restrict__ D2g, float* __restrict__ Yg,
                                            float* __restrict__ Ag, float* __restrict__ rowsumg) {
  const int b = blockIdx.x;
  const int l = threadIdx.x;
  if (l >= 16) return;                 // uniform exec for the whole DP
  const float* __restrict__ D2b = D2g + (size_t)b * TPAD * 16;
  float* __restrict__ Yb = Yg + (size_t)b * TPAD * 16;
  float* __restrict__ Ab = Ag + (size_t)b * TPAD * 16;

  // ================= forward =================
  {
    float m1, e1, m2, e2;              // (m,e) of diagonals d-1, d-2
    // d = 0: only (0,0) valid; y(0,0) = D2(0,0) exactly
    {
      float D0 = D2b[l];
      m1 = (l == 0) ? D0 : INFV;
      e1 = 1.f;
      m2 = INFV; e2 = 1.f;
      Yb[l] = m1;                      // y = m - log2(1) = m
    }
    // prologue d = 1..15 (masked)
#pragma unroll
    for (int d = 1; d < 16; ++d) {
      int t = d - l;
      int tc = t >= 0 ? t : 0;
      float D = D2b[tc * 16 + l];
      float a_m = dpp_shr1_inf(m1), a_e = dpp_shr1_z(e1);
      float c_m = dpp_shr1_inf(m2), c_e = dpp_shr1_z(e2);
      float mt = fminf(fminf(a_m, m1), c_m);
      float e = __builtin_amdgcn_exp2f(mt - a_m) * a_e
              + __builtin_amdgcn_exp2f(mt - m1) * e1
              + __builtin_amdgcn_exp2f(mt - c_m) * c_e;
      float m = mt + D;
      if (t < 0) { m = INFV; e = 1.f; }
      Yb[tc * 16 + l] = m - __builtin_amdgcn_logf(e);
      m2 = m1; e2 = e1; m1 = m; e1 = e;
    }
    // main body d = 16..2047: all lanes valid, mask-free, distance-2 prefetch
    const float* pD = D2b + (16 * 16 - 15 * l);
    float* pY = Yb + (16 * 16 - 15 * l);
    float cur[8], nx1[8];
#pragma unroll
    for (int j = 0; j < 8; ++j) cur[j] = pD[j * 16];
#pragma unroll
    for (int j = 0; j < 8; ++j) nx1[j] = pD[128 + j * 16];
    pD += 256;
#pragma unroll 1
    for (int d0 = 16; d0 < 2048; d0 += 8) {
      float nx2[8];
#pragma unroll
      for (int j = 0; j < 8; ++j) nx2[j] = pD[j * 16];   // over-reads land in dump region (<= row 2063)
      pD += 128;
#pragma unroll
      for (int j = 0; j < 8; ++j) {
        float a_m = dpp_shr1_inf(m1), a_e = dpp_shr1_z(e1);
        float c_m = dpp_shr1_inf(m2), c_e = dpp_shr1_z(e2);
        float mt = fminf(fminf(a_m, m1), c_m);
        float e = __builtin_amdgcn_exp2f(mt - a_m) * a_e
                + __builtin_amdgcn_exp2f(mt - m1) * e1
                + __builtin_amdgcn_exp2f(mt - c_m) * c_e;
        float m = mt + cur[j];
        pY[j * 16] = m - __builtin_amdgcn_logf(e);
        m2 = m1; e2 = e1; m1 = m; e1 = e;
      }
      pY += 128;
#pragma unroll
      for (int j = 0; j < 8; ++j) { cur[j] = nx1[j]; nx1[j] = nx2[j]; }
    }
    // epilogue d = 2048..2056 (masked); t>=2048 lanes store INFV into dump rows, which is
    // exactly the boundary value the backward start block reads.
#pragma unroll
    for (int dd = 0; dd < 9; ++dd) {
      int d = 2048 + dd;
      int t = d - l;                   // <= 2056 < TPAD
      float D = D2b[t * 16 + l];
      float a_m = dpp_shr1_inf(m1), a_e = dpp_shr1_z(e1);
      float c_m = dpp_shr1_inf(m2), c_e = dpp_shr1_z(e2);
      float mt = fminf(fminf(a_m, m1), c_m);
      float e = __builtin_amdgcn_exp2f(mt - a_m) * a_e
              + __builtin_amdgcn_exp2f(mt - m1) * e1
              + __builtin_amdgcn_exp2f(mt - c_m) * c_e;
      float m = mt + D;
      if (t >= T_) { m = INFV; e = 1.f; }
      Yb[t * 16 + l] = m - __builtin_amdgcn_logf(e);
      m2 = m1; e2 = e1; m1 = m; e1 = e;
    }
  }

  asm volatile("s_waitcnt vmcnt(0)" ::: "memory");   // forward Y stores -> backward Y loads
  __syncthreads();

  // ================= backward =================
  {
    float E1 = 0.f, E2 = 0.f;          // E of diagonals d+1, d+2
    float m1 = 0.f, m2 = 0.f;          // (Y - D2) of diagonals d+1, d+2
    float rsum = 0.f;
    // start block d = 2056..2048 (seed at d=2056, lane 9)
#pragma unroll
    for (int dd = 0; dd < 9; ++dd) {
      int t = (2056 - dd) - l;         // 2033..2056, inside padded region
      float yld = Yb[t * 16 + l];
      float dld = D2b[t * 16 + l];
      float g1 = fminf(dpp_shl1_z(m1) - yld, 0.f);
      float g2 = fminf(m1 - yld, 0.f);
      float g3 = fminf(dpp_shl1_z(m2) - yld, 0.f);
      float En = __builtin_amdgcn_exp2f(g1) * dpp_shl1_z(E1)
               + __builtin_amdgcn_exp2f(g2) * E1
               + __builtin_amdgcn_exp2f(g3) * dpp_shl1_z(E2);
      if (dd == 0) En = (l == 9) ? 1.f : 0.f;
      Ab[t * 16 + l] = En;
      rsum += En;
      E2 = E1; E1 = En; m2 = m1; m1 = yld - dld;
    }
    // main body d = 2047..16: weight precompute per block (off E-chain), distance-2 prefetch
    const float* pDr = D2b + (16 * 2047 - 15 * l);
    const float* pYr = Yb + (16 * 2047 - 15 * l);
    float* pAr = Ab + (16 * 2047 - 15 * l);
    float yc[8], dc[8], yn1[8], dn1[8];
#pragma unroll
    for (int j = 0; j < 8; ++j) { yc[j] = pYr[-16 * j]; dc[j] = pDr[-16 * j]; }
#pragma unroll
    for (int j = 0; j < 8; ++j) { yn1[j] = pYr[-128 - 16 * j]; dn1[j] = pDr[-128 - 16 * j]; }
    pDr -= 256; pYr -= 256;
#pragma unroll 1
    for (int d0 = 2047; d0 >= 23; d0 -= 8) {
      float yn2[8], dn2[8];
      if (d0 >= 39) {                  // block d0-16 exists only while d0-16 >= 23
#pragma unroll
        for (int j = 0; j < 8; ++j) { yn2[j] = pYr[-16 * j]; dn2[j] = pDr[-16 * j]; }
        pDr -= 128; pYr -= 128;
      }
      // weights for this block: independent of E (pure function of loaded diagonals)
      float w1[8], w2[8], w3[8];
#pragma unroll
      for (int j = 0; j < 8; ++j) {
        float yld = yc[j];
        float g1 = fminf(dpp_shl1_z(m1) - yld, 0.f);
        float g2 = fminf(m1 - yld, 0.f);
        float g3 = fminf(dpp_shl1_z(m2) - yld, 0.f);
        w1[j] = __builtin_amdgcn_exp2f(g1);
        w2[j] = __builtin_amdgcn_exp2f(g2);
        w3[j] = __builtin_amdgcn_exp2f(g3);
        m2 = m1; m1 = yld - dc[j];
      }
      // E-chain: dpp -> fma x3 per step
#pragma unroll
      for (int j = 0; j < 8; ++j) {
        float En = w1[j] * dpp_shl1_z(E1) + w2[j] * E1 + w3[j] * dpp_shl1_z(E2);
        pAr[-16 * j] = En;
        rsum += En;
        E2 = E1; E1 = En;
      }
      pAr -= 128;
#pragma unroll
      for (int j = 0; j < 8; ++j) { yc[j] = yn1[j]; dc[j] = dn1[j]; yn1[j] = yn2[j]; dn1[j] = dn2[j]; }
    }
    // end block d = 15..0 (masked; invalid lanes redirected to dump row 2063, forced 0)
#pragma unroll
    for (int dd = 0; dd < 16; ++dd) {
      int d = 15 - dd;
      int t = d - l;
      int tc = t >= 0 ? t : 2063;
      float yld = Yb[tc * 16 + l];
      float dld = D2b[tc * 16 + l];
      float g1 = fminf(dpp_shl1_z(m1) - yld, 0.f);
      float g2 = fminf(m1 - yld, 0.f);
      float g3 = fminf(dpp_shl1_z(m2) - yld, 0.f);
      float En = __builtin_amdgcn_exp2f(g1) * dpp_shl1_z(E1)
               + __builtin_amdgcn_exp2f(g2) * E1
               + __builtin_amdgcn_exp2f(g3) * dpp_shl1_z(E2);
      En = (t >= 0) ? En : 0.f;
      Ab[tc * 16 + l] = En;
      rsum += En;
      E2 = E1; E1 = En; m2 = m1; m1 = yld - dld;
    }
    if (l < NP) rowsumg[b * 16 + l] = rsum;
  }
}

// ---------------- K5: out3raw[b,c,p] += sum_t h[b,c,t]*E[b,p,t] ----------------
__global__ __launch_bounds__(256) void k5_out3(const float* __restrict__ h, const float* __restrict__ Ag,
                                               float* __restrict__ out3raw) {
  const int tc = blockIdx.x, b = blockIdx.y, tid = threadIdx.x;
  __shared__ float As[128 * 16];
  const float* Ab = Ag + ((size_t)b * TPAD + tc * 128) * 16;
#pragma unroll
  for (int k = 0; k < 2; ++k) {
    int i4 = tid + k * 256;
    *(float4*)(&As[i4 * 4]) = *(const float4*)(Ab + i4 * 4);
  }
  __syncthreads();
  const int c = tid;
  const float* hb = h + ((size_t)b * CH + c) * T_ + tc * 128;
  float acc[NP];
#pragma unroll
  for (int p = 0; p < NP; ++p) acc[p] = 0.f;
  for (int t4 = 0; t4 < 32; ++t4) {
    float4 hv = *(const float4*)(hb + t4 * 4);
    float he[4] = {hv.x, hv.y, hv.z, hv.w};
#pragma unroll
    for (int u = 0; u < 4; ++u) {
      const float* ar = &As[(t4 * 4 + u) * 16];
#pragma unroll
      for (int p = 0; p < NP; ++p) acc[p] += he[u] * ar[p];
    }
  }
  float* dst = out3raw + ((size_t)(b * CH + c)) * NP;
#pragma unroll
  for (int p = 0; p < NP; ++p) atomicAdd(dst + p, acc[p]);
}

// ---------------- K6a: proj, attn softmax, ind argmax ----------------
__global__ __launch_bounds__(64) void k6a_head(const float* __restrict__ out1w, const float* __restrict__ out2w,
                                               const float* __restrict__ out3raw, const float* __restrict__ rowsumg,
                                               const float* __restrict__ enc_w, const float* __restrict__ enc_b,
                                               const float* __restrict__ sw, float* __restrict__ attn_out,
                                               float* __restrict__ ind_sum) {
  const int b = blockIdx.x;
  const int lane = threadIdx.x;
  float a1 = 0.f, a2[NP], a3[NP];
#pragma unroll
  for (int p = 0; p < NP; ++p) { a2[p] = 0.f; a3[p] = 0.f; }
#pragma unroll
  for (int k = 0; k < 4; ++k) {
    const int c = lane + k * 64;
    const float ew = enc_w[c];
    a1 += out1w[b * CH + c] * ew;
    const float* o2 = out2w + ((size_t)(b * CH + c)) * NP;
    const float* o3 = out3raw + ((size_t)(b * CH + c)) * NP;
#pragma unroll
    for (int p = 0; p < NP; ++p) { a2[p] += o2[p] * ew; a3[p] += o3[p] * ew; }
  }
#pragma unroll
  for (int st = 32; st >= 1; st >>= 1) {
    a1 += __shfl_xor(a1, st);
#pragma unroll
    for (int p = 0; p < NP; ++p) { a2[p] += __shfl_xor(a2[p], st); a3[p] += __shfl_xor(a3[p], st); }
  }
  __shared__ float proj[30];
  __shared__ float indv[90];
  if (lane == 0) {
#pragma unroll
    for (int p = 0; p < NP; ++p) {
      proj[p] = a1;
      proj[10 + p] = a2[p];
      proj[20 + p] = a3[p] / rowsumg[b * 16 + p];
    }
  }
  __syncthreads();
  if (lane < 30) {
    const float pj = proj[lane];
    const float eb = enc_b[0];
    float lg[30];
    float mx = -1e30f;
#pragma unroll
    for (int j = 0; j < 30; ++j) { lg[j] = pj * sw[j] + eb; mx = fmaxf(mx, lg[j]); }
    float ssum = 0.f;
#pragma unroll
    for (int j = 0; j < 30; ++j) { lg[j] = expf(lg[j] - mx); ssum += lg[j]; }
    const float inv = 1.f / ssum;
    float m0 = 0.f, m1 = 0.f, m2 = 0.f;
#pragma unroll
    for (int j = 0; j < 30; ++j) {
      const float av = lg[j] * inv;
      attn_out[(size_t)b * 900 + lane * 30 + j] = av;
      if (j < 10) m0 += av; else if (j < 20) m1 += av; else m2 += av;
    }
    indv[lane] = m0 * 0.1f; indv[30 + lane] = m1 * 0.1f; indv[60 + lane] = m2 * 0.1f;
  }
  __syncthreads();
  if (lane == 0) {
    float best = -1e30f; int bi = 0;
    for (int k = 0; k < 90; ++k) { const float v = indv[k]; if (v > best) { best = v; bi = k; } }
    atomicAdd(ind_sum, (float)bi);
  }
}

// ---------------- K7a: one = selected branch (also emits op scalar) ----------------
__global__ __launch_bounds__(256) void k7a_one(const float* __restrict__ out1w, const float* __restrict__ out2w,
                                               const float* __restrict__ out3raw, const float* __restrict__ rowsumg,
                                               const float* __restrict__ indws, float* __restrict__ one_out,
                                               float* __restrict__ op_out) {
  const int b = blockIdx.x, c = threadIdx.x;
  const float ind = indws[0] * (1.f / 64.f);
  const int op = ind < 0.6f ? 0 : (ind < 1.6f ? 1 : 2);
  if (b == 0 && c == 0) op_out[0] = (float)op;
  float* dst = one_out + ((size_t)(b * CH + c)) * NP;
  if (op == 0) {
    const float v = out1w[b * CH + c];
#pragma unroll
    for (int p = 0; p < NP; ++p) dst[p] = v;
  } else if (op == 1) {
    const float* s = out2w + ((size_t)(b * CH + c)) * NP;
#pragma unroll
    for (int p = 0; p < NP; ++p) dst[p] = s[p];
  } else {
    const float* s = out3raw + ((size_t)(b * CH + c)) * NP;
#pragma unroll
    for (int p = 0; p < NP; ++p) dst[p] = s[p] / rowsumg[b * 16 + p];
  }
}

// ---------------- K7b: ensemble = concat_out @ attn ----------------
__global__ __launch_bounds__(256) void k7b_ens(const float* __restrict__ out1w, const float* __restrict__ out2w,
                                               const float* __restrict__ out3raw, const float* __restrict__ rowsumg,
                                               const float* __restrict__ attn, float* __restrict__ ens) {
  const int b = blockIdx.x, tid = threadIdx.x;
  __shared__ float at[900];
  __shared__ float s0[30];
  __shared__ float irs[NP];
  for (int k = tid; k < 900; k += 256) at[k] = attn[(size_t)b * 900 + k];
  if (tid < NP) irs[tid] = 1.f / rowsumg[b * 16 + tid];
  __syncthreads();
  if (tid < 30) {
    float s = 0.f;
    for (int i = 0; i < 10; ++i) s += at[i * 30 + tid];
    s0[tid] = s;
  }
  __syncthreads();
  const int c = tid;
  const float o1 = out1w[b * CH + c];
  float o2[NP], o3[NP];
  const float* p2 = out2w + ((size_t)(b * CH + c)) * NP;
  const float* p3 = out3raw + ((size_t)(b * CH + c)) * NP;
#pragma unroll
  for (int p = 0; p < NP; ++p) { o2[p] = p2[p]; o3[p] = p3[p] * irs[p]; }
  float* dst = ens + ((size_t)(b * CH + c)) * 30;
#pragma unroll
  for (int j = 0; j < 30; ++j) {
    float acc = o1 * s0[j];
#pragma unroll
    for (int p = 0; p < NP; ++p) acc += o2[p] * at[(10 + p) * 30 + j] + o3[p] * at[(20 + p) * 30 + j];
    dst[j] = acc;
  }
}

// ---------------- K7c: z1 partial GEMM (one[64x2560] @ w1^T -> [64x512]) ----------------
__global__ __launch_bounds__(256) void k7c_z1(const float* __restrict__ one_, const float* __restrict__ w1,
                                              float* __restrict__ z1acc) {
  const int kt = blockIdx.x;  // 8
  const int mt = blockIdx.y;  // 40
  const int tid = threadIdx.x;
  __shared__ float os[64][65];
  __shared__ float wsl[64][65];
  const int k0 = kt * 64, m0 = mt * 64;
#pragma unroll
  for (int k = 0; k < 4; ++k) {
    int idx = tid + k * 256;
    int r = idx >> 4, q = (idx & 15) * 4;
    float4 v1 = *(const float4*)(one_ + (size_t)r * 2560 + m0 + q);
    os[r][q] = v1.x; os[r][q + 1] = v1.y; os[r][q + 2] = v1.z; os[r][q + 3] = v1.w;
    float4 v2 = *(const float4*)(w1 + (size_t)(k0 + r) * 2560 + m0 + q);
    wsl[r][q] = v2.x; wsl[r][q + 1] = v2.y; wsl[r][q + 2] = v2.z; wsl[r][q + 3] = v2.w;
  }
  __syncthreads();
  const int bg = tid >> 4, kg = tid & 15;
  float acc[4][4];
#pragma unroll
  for (int i = 0; i < 4; ++i)
#pragma unroll
    for (int j = 0; j < 4; ++j) acc[i][j] = 0.f;
  for (int m = 0; m < 64; ++m) {
    float ov[4], wv[4];
#pragma unroll
    for (int i = 0; i < 4; ++i) { ov[i] = os[bg * 4 + i][m]; wv[i] = wsl[kg * 4 + i][m]; }
#pragma unroll
    for (int i = 0; i < 4; ++i)
#pragma unroll
      for (int j = 0; j < 4; ++j) acc[i][j] += ov[i] * wv[j];
  }
#pragma unroll
  for (int i = 0; i < 4; ++i)
#pragma unroll
    for (int j = 0; j < 4; ++j)
      atomicAdd(&z1acc[(size_t)(bg * 4 + i) * 512 + k0 + kg * 4 + j], acc[i][j]);
}

// ---------------- K7d: z2 partial GEMM (relu(z1+b1)[64x512] @ w2^T -> [64x1024]) ----------------
__global__ __launch_bounds__(256) void k7d_z2(const float* __restrict__ z1acc, const float* __restrict__ db1,
                                              const float* __restrict__ w2, float* __restrict__ z2acc) {
  const int kt = blockIdx.x;  // 16
  const int mt = blockIdx.y;  // 8
  const int tid = threadIdx.x;
  __shared__ float os[64][65];
  __shared__ float wsl[64][65];
  const int k0 = kt * 64, m0 = mt * 64;
#pragma unroll
  for (int k = 0; k < 4; ++k) {
    int idx = tid + k * 256;
    int r = idx >> 4, q = (idx & 15) * 4;
    float4 v1 = *(const float4*)(z1acc + (size_t)r * 512 + m0 + q);
    float4 bv = *(const float4*)(db1 + m0 + q);
    os[r][q] = fmaxf(v1.x + bv.x, 0.f); os[r][q + 1] = fmaxf(v1.y + bv.y, 0.f);
    os[r][q + 2] = fmaxf(v1.z + bv.z, 0.f); os[r][q + 3] = fmaxf(v1.w + bv.w, 0.f);
    float4 v2 = *(const float4*)(w2 + (size_t)(k0 + r) * 512 + m0 + q);
    wsl[r][q] = v2.x; wsl[r][q + 1] = v2.y; wsl[r][q + 2] = v2.z; wsl[r][q + 3] = v2.w;
  }
  __syncthreads();
  const int bg = tid >> 4, kg = tid & 15;
  float acc[4][4];
#pragma unroll
  for (int i = 0; i < 4; ++i)
#pragma unroll
    for (int j = 0; j < 4; ++j) acc[i][j] = 0.f;
  for (int m = 0; m < 64; ++m) {
    float ov[4], wv[4];
#pragma unroll
    for (int i = 0; i < 4; ++i) { ov[i] = os[bg * 4 + i][m]; wv[i] = wsl[kg * 4 + i][m]; }
#pragma unroll
    for (int i = 0; i < 4; ++i)
#pragma unroll
      for (int j = 0; j < 4; ++j) acc[i][j] += ov[i] * wv[j];
  }
#pragma unroll
  for (int i = 0; i < 4; ++i)
#pragma unroll
    for (int j = 0; j < 4; ++j)
      atomicAdd(&z2acc[(size_t)(bg * 4 + i) * 1024 + k0 + kg * 4 + j], acc[i][j]);
}

// ---------------- K7e: out = relu(z2+b2) @ w3^T + b3 ----------------
__global__ __launch_bounds__(64) void k7e_out(const float* __restrict__ z2acc, const float* __restrict__ db2,
                                              const float* __restrict__ w3, const float* __restrict__ db3,
                                              float* __restrict__ outp) {
  const int b = blockIdx.x, lane = threadIdx.x;
  float acc[NP];
#pragma unroll
  for (int n = 0; n < NP; ++n) acc[n] = 0.f;
  for (int j = lane; j < 1024; j += 64) {
    float zv = z2acc[(size_t)b * 1024 + j] + db2[j];
    zv = fmaxf(zv, 0.f);
#pragma unroll
    for (int n = 0; n < NP; ++n) acc[n] += zv * w3[(size_t)n * 1024 + j];
  }
#pragma unroll
  for (int n = 0; n < NP; ++n)
#pragma unroll
    for (int st = 32; st >= 1; st >>= 1) acc[n] += __shfl_xor(acc[n], st);
  if (lane == 0) {
#pragma unroll
    for (int n = 0; n < NP; ++n) outp[b * NP + n] = acc[n] + db3[n];
  }
}

// ---------------- launch ----------------
extern "C" void kernel_launch(void* const* d_in, const int* in_sizes, int n_in,
                              void* d_out, int out_size, void* d_ws, size_t ws_size,
                              hipStream_t stream) {
  (void)in_sizes; (void)n_in; (void)out_size; (void)ws_size;
  const float* x      = (const float*)d_in[0];
  const float* conv_w = (const float*)d_in[1];
  const float* conv_b = (const float*)d_in[2];
  const float* protos = (const float*)d_in[3];
  const float* sw     = (const float*)d_in[4];
  const float* enc_w  = (const float*)d_in[5];
  const float* enc_b  = (const float*)d_in[6];
  const float* dw1    = (const float*)d_in[7];
  const float* db1    = (const float*)d_in[8];
  const float* dw2    = (const float*)d_in[9];
  const float* db2    = (const float*)d_in[10];
  const float* dw3    = (const float*)d_in[11];
  const float* db3    = (const float*)d_in[12];
  float* out = (float*)d_out;
  float* ws  = (float*)d_ws;

  float* D2g     = ws + OFF_D2;
  float* Yg      = ws + OFF_Y;
  float* Ag      = ws + OFF_A;
  float* rowsumg = ws + OFF_RS;
  float* out1w   = ws + OFF_O1;
  float* out2w   = ws + OFF_O2;
  float* out3raw = ws + OFF_O3;
  float* indws   = ws + OFF_IND;
  float* z1acc   = ws + OFF_Z1;
  float* z2acc   = ws + OFF_Z2;
  float* h       = out + DO_H;

  // zero the atomic accumulators (out2w raw sums, out3raw, ind, z1acc, z2acc)
  hipMemsetAsync(ws + OFF_O2, 0, (WS_END - OFF_O2) * sizeof(float), stream);

  k1_conv<<<dim3(16, 4, 64), 256, 0, stream>>>(x, conv_w, conv_b, h, out2w);
  k2_d2<<<dim3(8, 64), 256, 0, stream>>>(h, protos, D2g);
  k3b_fin<<<64, 256, 0, stream>>>(out2w, out1w);
  k4_dp<<<64, 64, 0, stream>>>(D2g, Yg, Ag, rowsumg);
  k5_out3<<<dim3(16, 64), 256, 0, stream>>>(h, Ag, out3raw);
  k6a_head<<<64, 64, 0, stream>>>(out1w, out2w, out3raw, rowsumg, enc_w, enc_b, sw,
                                  out + DO_ATT, indws);
  k7a_one<<<64, 256, 0, stream>>>(out1w, out2w, out3raw, rowsumg, indws, out + DO_ONE,
                                  out + DO_OP);
  k7b_ens<<<64, 256, 0, stream>>>(out1w, out2w, out3raw, rowsumg, out + DO_ATT, out + DO_ENS);
  k7c_z1<<<dim3(8, 40), 256, 0, stream>>>(out + DO_ONE, dw1, z1acc);
  k7d_z2<<<dim3(16, 8), 256, 0, stream>>>(z1acc, db1, dw2, z2acc);
  k7e_out<<<64, 64, 0, stream>>>(z2acc, db2, dw3, db3, out + DO_OUT);
}

// Round 4
// 683.497 us; speedup vs baseline: 1.3748x; 1.3748x over previous
//
#include <hip/hip_runtime.h>

// ---------------- constants ----------------
#define B_    64
#define CIN   64
#define CH    256
#define T_    2048
#define NP    10
#define INVLN2 1.44269504088896340736f
#define INFV  1e10f
#define FPAD  16          // front-pad rows of diag buffers
#define DROWS 2088        // diag rows incl pads
#define SDIAG 33408       // DROWS*16 per batch
#define BFPAD 16
#define BKROWS 2096       // per-batch b rows incl pads

// d_out element offsets (float32)
static const size_t DO_H   = 0;
static const size_t DO_OUT = 33554432;
static const size_t DO_ENS = 33555072;
static const size_t DO_ONE = 34046592;   // holds out2 raw sums -> means -> "one"
static const size_t DO_OP  = 34210432;
static const size_t DO_ATT = 34210433;

// d_ws element offsets (float32)
static const size_t OFF_D2 = 0;          // [64][2088][16] diag layout
static const size_t OFF_RF = 2138112;    // [64][2088][16] forward R'
static const size_t OFF_Q  = 4276224;    // [64][2088][16] reverse Q = R~' - D'
static const size_t OFF_BK = 6414336;    // [64][2096] diag-min keys -> floats; later z1/z2
static const size_t OFF_RS = 6548480;    // [64][16] rowsums (zeroed)
static const size_t OFF_RT = 6549504;    // [64] rtot'
static const size_t OFF_O1 = 6549568;    // [64][256] out1 means
static const size_t OFF_O3 = 6565952;    // [64][256][10] out3 raw (zeroed)
static const size_t OFF_IND= 6729792;    // [0]=ind sum (zeroed)
static const size_t WS_END = 6729808;    // 26.92 MB

// lane i <- lane i-1 within 16-lane row; shifted-in lanes get INFV
__device__ __forceinline__ float dpp_shr1_inf(float x) {
  return __int_as_float(__builtin_amdgcn_update_dpp(
      __float_as_int(INFV), __float_as_int(x), 0x111, 0xf, 0xf, false));
}
// lane i <- lane i-1 within 16-lane row; shifted-in lanes get 0
__device__ __forceinline__ float dpp_shr1_z(float x) {
  return __int_as_float(__builtin_amdgcn_update_dpp(0, __float_as_int(x), 0x111, 0xf, 0xf, true));
}
// 16-lane row prefix sum; lane 15 of each row holds the row total
__device__ __forceinline__ float row_prefix_sum16(float v) {
  v += __int_as_float(__builtin_amdgcn_update_dpp(0, __float_as_int(v), 0x111, 0xf, 0xf, true));
  v += __int_as_float(__builtin_amdgcn_update_dpp(0, __float_as_int(v), 0x112, 0xf, 0xf, true));
  v += __int_as_float(__builtin_amdgcn_update_dpp(0, __float_as_int(v), 0x114, 0xf, 0xf, true));
  v += __int_as_float(__builtin_amdgcn_update_dpp(0, __float_as_int(v), 0x118, 0xf, 0xf, true));
  return v;
}
__device__ __forceinline__ unsigned fkey(float f) {
  unsigned u = __float_as_uint(f);
  return (u & 0x80000000u) ? ~u : (u | 0x80000000u);
}

// ---------------- K1: h = relu(conv_w @ x + b), fused STP raw segment sums ----------------
__global__ __launch_bounds__(256) void k1_conv(const float* __restrict__ x, const float* __restrict__ w,
                                               const float* __restrict__ bias, float* __restrict__ h,
                                               float* __restrict__ out2w) {
  const int tt = blockIdx.x, ot = blockIdx.y, b = blockIdx.z;
  const int tid = threadIdx.x;
  __shared__ float xs[64][132];
  __shared__ float wt[64][64];
  const int t0 = tt * 128, o0 = ot * 64;
  {
    const float* xb = x + ((size_t)b * CIN) * T_ + t0;
#pragma unroll
    for (int k = 0; k < 8; ++k) {
      int idx = tid + k * 256;
      int c = idx >> 5, q = idx & 31;
      float4 v = *(const float4*)(xb + (size_t)c * T_ + q * 4);
      *(float4*)(&xs[c][q * 4]) = v;
    }
#pragma unroll
    for (int k = 0; k < 4; ++k) {
      int idx = tid + k * 256;
      int o = idx >> 4, c4 = (idx & 15) * 4;
      float4 v = *(const float4*)(w + (size_t)(o0 + o) * 64 + c4);
      wt[c4 + 0][o] = v.x; wt[c4 + 1][o] = v.y; wt[c4 + 2][o] = v.z; wt[c4 + 3][o] = v.w;
    }
  }
  __syncthreads();
  const int og = tid >> 4, tg = tid & 15;
  float acc[4][8];
#pragma unroll
  for (int i = 0; i < 4; ++i)
#pragma unroll
    for (int j = 0; j < 8; ++j) acc[i][j] = 0.f;
  for (int c = 0; c < 64; ++c) {
    float a0 = wt[c][og * 4 + 0], a1 = wt[c][og * 4 + 1], a2 = wt[c][og * 4 + 2], a3 = wt[c][og * 4 + 3];
    float xv[8];
#pragma unroll
    for (int j = 0; j < 8; ++j) xv[j] = xs[c][tg * 8 + j];
#pragma unroll
    for (int j = 0; j < 8; ++j) {
      acc[0][j] += a0 * xv[j]; acc[1][j] += a1 * xv[j];
      acc[2][j] += a2 * xv[j]; acc[3][j] += a3 * xv[j];
    }
  }
  // segment geometry
  const int tb = t0 + tg * 8;
  int s_lo = tb / 204; if (s_lo > 9) s_lo = 9;
  int s_hi = (tb + 7) / 204; if (s_hi > 9) s_hi = 9;
  const int cross = (s_hi > s_lo) ? ((s_lo + 1) * 204 - tb) : 8;
  int sblock = t0 / 204; if (sblock > 9) sblock = 9;
  const bool crossB = (sblock < 9) && ((sblock + 1) * 204 < t0 + 128);

  float* hb = h + ((size_t)b * CH + o0) * T_ + t0;
#pragma unroll
  for (int i = 0; i < 4; ++i) {
    const float bv = bias[o0 + og * 4 + i];
    float vs[8];
#pragma unroll
    for (int j = 0; j < 8; ++j) vs[j] = fmaxf(acc[i][j] + bv, 0.f);
    float4 v0, v1;
    v0.x = vs[0]; v0.y = vs[1]; v0.z = vs[2]; v0.w = vs[3];
    v1.x = vs[4]; v1.y = vs[5]; v1.z = vs[6]; v1.w = vs[7];
    *(float4*)(&hb[(size_t)(og * 4 + i) * T_ + tg * 8]) = v0;
    *(float4*)(&hb[(size_t)(og * 4 + i) * T_ + tg * 8 + 4]) = v1;
    float sumA = 0.f, sumB = 0.f;
#pragma unroll
    for (int j = 0; j < 8; ++j) { if (j < cross) sumA += vs[j]; else sumB += vs[j]; }
    float cLo = ((s_lo == sblock) ? sumA : 0.f) + ((s_hi == sblock) ? sumB : 0.f);
    float cHi = ((s_lo == sblock + 1) ? sumA : 0.f) + ((s_hi == sblock + 1) ? sumB : 0.f);
    float rLo = row_prefix_sum16(cLo);
    float rHi = row_prefix_sum16(cHi);
    if (tg == 15) {
      float* o2p = out2w + ((size_t)(b * CH + o0 + og * 4 + i)) * NP;
      atomicAdd(o2p + sblock, rLo);
      if (crossB) atomicAdd(o2p + sblock + 1, rHi);
    }
  }
}

// ---------------- K2: D2diag[d][p] (log2-scaled) + per-diagonal min keys ----------------
__global__ __launch_bounds__(256) void k2_d2(const float* __restrict__ h, const float* __restrict__ protos,
                                             float* __restrict__ D2g, unsigned* __restrict__ bkey) {
  const int tt = blockIdx.x, b = blockIdx.y, tid = threadIdx.x;
  __shared__ float pl[2560];
  __shared__ float pn[NP];
  __shared__ unsigned smin[272];
#pragma unroll
  for (int k = 0; k < 10; ++k) pl[tid + k * 256] = protos[tid + k * 256];
  for (int i = tid; i < 272; i += 256) smin[i] = 0xFFFFFFFFu;
  __syncthreads();
  if (tid < NP) {
    float s = 0.f;
    for (int c = 0; c < CH; ++c) { float v = pl[c * NP + tid]; s += v * v; }
    pn[tid] = s;
  }
  __syncthreads();
  const int t0 = tt * 256;
  const int t = t0 + tid;
  const float* hb = h + (size_t)b * CH * T_ + t;
  float hn = 0.f, ph[NP];
#pragma unroll
  for (int p = 0; p < NP; ++p) ph[p] = 0.f;
  for (int c = 0; c < CH; ++c) {
    float hv = hb[(size_t)c * T_];
    hn += hv * hv;
#pragma unroll
    for (int p = 0; p < NP; ++p) ph[p] += pl[c * NP + p] * hv;
  }
  float* dst = D2g + (size_t)b * SDIAG + FPAD * 16;
#pragma unroll
  for (int p = 0; p < NP; ++p) {
    float dv = (pn[p] + hn - 2.f * ph[p]) * INVLN2;
    dst[(t + p) * 16 + p] = dv;
    atomicMin(&smin[tid + p], fkey(dv));
  }
  __syncthreads();
  unsigned* bk = bkey + (size_t)b * BKROWS + BFPAD + t0;
  for (int i = tid; i < 265; i += 256) atomicMin(&bk[i], smin[i]);
}

// ---------------- K3b: decode b keys; finalize out1/out2 means ----------------
__global__ __launch_bounds__(256) void k3b_fin(float* __restrict__ out2w, float* __restrict__ out1w,
                                               unsigned* __restrict__ bkey) {
  const int b = blockIdx.x, o = threadIdx.x;
  unsigned* bk = bkey + (size_t)b * BKROWS;
  for (int i = o; i < BKROWS; i += 256) {
    unsigned u = bk[i];
    float f = (u & 0x80000000u) ? __uint_as_float(u ^ 0x80000000u) : __uint_as_float(~u);
    ((float*)bk)[i] = f;
  }
  float* p = out2w + ((size_t)(b * CH + o)) * NP;
  float vals[NP], tot = 0.f;
#pragma unroll
  for (int s = 0; s < NP; ++s) { vals[s] = p[s]; tot += vals[s]; }
  out1w[b * CH + o] = tot * (1.f / 2048.f);
#pragma unroll
  for (int s = 0; s < 9; ++s) p[s] = vals[s] * (1.f / 204.f);
  p[9] = vals[9] * (1.f / 212.f);
}

// ---------------- K4: bidirectional soft-DTW DP (fwd + reverse in one wave) ----------------
// Lanes 0-15: forward DP on D'; lanes 16-31: reverse DP on D' reversed in (p,t).
// (m,e) rep: y = m - log2(e). Per-diagonal baseline b_d subtracted (R' small -> tiny f32 error).
// Group A stores y (Rf'); group B stores Q = y - (D - b) at [step][lane] ascending.
struct DPState { float m1, e1, amP, aeP, bP; };
__device__ __forceinline__ float dp_step(DPState& s, float cD, float bv, bool isB) {
  float a_m = dpp_shr1_inf(s.m1);
  float a_e = dpp_shr1_z(s.e1);
  float c_m = s.amP - s.bP;                        // diag d-2, re-shifted by b_{d-1}
  float mt = fminf(fminf(a_m, s.m1), c_m);
  float e = __builtin_amdgcn_exp2f(mt - a_m) * a_e
          + __builtin_amdgcn_exp2f(mt - s.m1) * s.e1
          + __builtin_amdgcn_exp2f(mt - c_m) * s.aeP;
  float m = mt + cD;
  float y = m - __builtin_amdgcn_logf(e);          // native log2
  s.amP = a_m; s.aeP = a_e; s.bP = bv;
  s.m1 = m; s.e1 = e;
  return isB ? (y - cD) : y;
}

__global__ __launch_bounds__(64) void k4_dp(const float* __restrict__ D2g, const float* __restrict__ bg,
                                            float* __restrict__ Rfg, float* __restrict__ Qg,
                                            float* __restrict__ rtotg) {
  const int b = blockIdx.x;
  const int l = threadIdx.x;
  if (l >= 32) return;
  const int grp = l >> 4, lr = l & 15;
  const bool isB = (grp != 0);
  const float* __restrict__ D2b = D2g + (size_t)b * SDIAG;
  const float* __restrict__ bb  = bg + (size_t)b * BKROWS;
  float* __restrict__ Sb = (grp == 0 ? Rfg : Qg) + (size_t)b * SDIAG;

  DPState st;
  // ---- d = 0 ----
  {
    float D0, b0;
    if (grp == 0) { D0 = D2b[FPAD * 16 + lr];              b0 = bb[BFPAD + 2056 * 0]; b0 = bb[BFPAD]; b0 = bb[BFPAD + 0]; }
    else          { D0 = D2b[(FPAD + 2056) * 16 + 9 - lr]; b0 = bb[BFPAD + 2056]; }
    if (grp == 0) b0 = bb[BFPAD + 0];
    float c0 = D0 - b0;
    st.m1 = (lr == 0) ? c0 : INFV; st.e1 = 1.f;
    st.amP = INFV; st.aeP = 1.f; st.bP = b0;
    Sb[FPAD * 16 + lr] = st.m1;
  }
  // ---- prefill main-loop blocks d=16..23 (cur) and 24..31 (n1) ----
  float ccur[8], bcur[8], n1D[8], n1B[8];
  {
    float cD0[8], cB0[8];
    if (grp == 0) {
#pragma unroll
      for (int j = 0; j < 8; ++j) {
        cD0[j] = D2b[(FPAD + 16 + j) * 16 + lr]; cB0[j] = bb[BFPAD + 16 + j];
        n1D[j] = D2b[(FPAD + 24 + j) * 16 + lr]; n1B[j] = bb[BFPAD + 24 + j];
      }
    } else {
#pragma unroll
      for (int j = 0; j < 8; ++j) {
        cD0[j] = D2b[(FPAD + 2056 - 16 - j) * 16 + 9 - lr]; cB0[j] = bb[BFPAD + 2056 - 16 - j];
        n1D[j] = D2b[(FPAD + 2056 - 24 - j) * 16 + 9 - lr]; n1B[j] = bb[BFPAD + 2056 - 24 - j];
      }
    }
#pragma unroll
    for (int j = 0; j < 8; ++j) { ccur[j] = cD0[j] - cB0[j]; bcur[j] = cB0[j]; }
  }
  // ---- prologue d = 1..15 (masked) ----
#pragma unroll
  for (int d = 1; d < 16; ++d) {
    float Dv, bv;
    if (grp == 0) { Dv = D2b[(FPAD + d) * 16 + lr];            bv = bb[BFPAD + d]; }
    else          { Dv = D2b[(FPAD + 2056 - d) * 16 + 9 - lr]; bv = bb[BFPAD + 2056 - d]; }
    float stv = dp_step(st, Dv - bv, bv, isB);
    if (lr > d) { st.m1 = INFV; st.e1 = 1.f; }
    Sb[(FPAD + d) * 16 + lr] = stv;
  }
  // ---- main loop d = 16..2055, blocks of 8, distance-2 prefetch ----
  const float* pDl; const float* pBl; int drD, drB;
  if (grp == 0) { pDl = D2b + (FPAD + 32) * 16 + lr;            pBl = bb + BFPAD + 32;        drD = 128;  drB = 8; }
  else          { pDl = D2b + (FPAD + 2056 - 32) * 16 + 9 - lr; pBl = bb + BFPAD + 2056 - 32; drD = -128; drB = -8; }
  float* pSl = Sb + (FPAD + 16) * 16 + lr;
#pragma unroll 1
  for (int d0 = 16; d0 <= 2048; d0 += 8) {
    float n2D[8], n2B[8];
    if (d0 <= 2032) {
      if (grp == 0) {
#pragma unroll
        for (int j = 0; j < 8; ++j) { n2D[j] = pDl[j * 16]; n2B[j] = pBl[j]; }
      } else {
#pragma unroll
        for (int j = 0; j < 8; ++j) { n2D[j] = pDl[-j * 16]; n2B[j] = pBl[-j]; }
      }
      pDl += drD; pBl += drB;
    }
    float cnx[8], bnx[8];
#pragma unroll
    for (int j = 0; j < 8; ++j) { cnx[j] = n1D[j] - n1B[j]; bnx[j] = n1B[j]; }
#pragma unroll
    for (int j = 0; j < 8; ++j) {
      float stv = dp_step(st, ccur[j], bcur[j], isB);
      pSl[j * 16] = stv;
    }
    pSl += 128;
#pragma unroll
    for (int j = 0; j < 8; ++j) { ccur[j] = cnx[j]; bcur[j] = bnx[j]; n1D[j] = n2D[j]; n1B[j] = n2B[j]; }
  }
  // ---- final step d = 2056 ----
  {
    float Dv, bv;
    if (grp == 0) { Dv = D2b[(FPAD + 2056) * 16 + lr]; bv = bb[BFPAD + 2056]; }
    else          { Dv = D2b[FPAD * 16 + 9 - lr];      bv = bb[BFPAD + 0]; }
    float stv = dp_step(st, Dv - bv, bv, isB);
    Sb[(FPAD + 2056) * 16 + lr] = stv;
    if (l == 9) rtotg[b] = stv;        // group A, lane 9 = cell (9,2047)
  }
}

// ---------------- K5: E = exp2(rtot - Rf' - Q); rowsums; out3raw GEMM ----------------
__global__ __launch_bounds__(256) void k5_out3(const float* __restrict__ h, const float* __restrict__ Rfg,
                                               const float* __restrict__ Qg, const float* __restrict__ rtotg,
                                               float* __restrict__ out3raw, float* __restrict__ rowsumg) {
  const int tc = blockIdx.x, b = blockIdx.y, tid = threadIdx.x;
  const int t0 = tc * 128;
  __shared__ float Rfs[2304];
  __shared__ float Qs[2304];
  __shared__ float Es[2048];
  __shared__ float rsl[272];
  const float* Rfb = Rfg + (size_t)b * SDIAG + (size_t)(FPAD + t0) * 16;
  const int qlo = 2056 - t0 - 143;
  const float* Qb = Qg + (size_t)b * SDIAG + (size_t)(FPAD + qlo) * 16;
#pragma unroll
  for (int k = 0; k < 3; ++k) {
    int i4 = tid + k * 256;
    if (i4 < 576) {
      ((float4*)Rfs)[i4] = ((const float4*)Rfb)[i4];
      ((float4*)Qs)[i4]  = ((const float4*)Qb)[i4];
    }
  }
  const float rtot = rtotg[b];
  __syncthreads();
  const int p = tid & 15, w = tid >> 4;
  float part = 0.f;
#pragma unroll
  for (int k = 0; k < 8; ++k) {
    const int i = k * 16 + w;
    float E = 0.f;
    if (p < NP) {
      float rf = Rfs[(i + p) * 16 + p];
      float q  = Qs[(143 - i - p) * 16 + (9 - p)];
      E = __builtin_amdgcn_exp2f(rtot - rf - q);
      part += E;
    }
    Es[i * 16 + p] = E;
  }
  rsl[p * 17 + w] = part;
  __syncthreads();
  if (tid < NP) {
    float s = 0.f;
#pragma unroll
    for (int w2 = 0; w2 < 16; ++w2) s += rsl[tid * 17 + w2];
    atomicAdd(&rowsumg[b * 16 + tid], s);
  }
  const int c = tid;
  const float* hb = h + ((size_t)b * CH + c) * T_ + t0;
  float acc[NP];
#pragma unroll
  for (int pp = 0; pp < NP; ++pp) acc[pp] = 0.f;
  for (int t4 = 0; t4 < 32; ++t4) {
    float4 hv = *(const float4*)(hb + t4 * 4);
    float he[4] = {hv.x, hv.y, hv.z, hv.w};
#pragma unroll
    for (int u = 0; u < 4; ++u) {
      const float* ar = &Es[(t4 * 4 + u) * 16];
#pragma unroll
      for (int pp = 0; pp < NP; ++pp) acc[pp] += he[u] * ar[pp];
    }
  }
  float* dst = out3raw + ((size_t)(b * CH + c)) * NP;
#pragma unroll
  for (int pp = 0; pp < NP; ++pp) atomicAdd(dst + pp, acc[pp]);
}

// ---------------- K6a: proj, attn softmax, ind argmax ----------------
__global__ __launch_bounds__(64) void k6a_head(const float* __restrict__ out1w, const float* __restrict__ out2w,
                                               const float* __restrict__ out3raw, const float* __restrict__ rowsumg,
                                               const float* __restrict__ enc_w, const float* __restrict__ enc_b,
                                               const float* __restrict__ sw, float* __restrict__ attn_out,
                                               float* __restrict__ ind_sum) {
  const int b = blockIdx.x;
  const int lane = threadIdx.x;
  float a1 = 0.f, a2[NP], a3[NP];
#pragma unroll
  for (int p = 0; p < NP; ++p) { a2[p] = 0.f; a3[p] = 0.f; }
#pragma unroll
  for (int k = 0; k < 4; ++k) {
    const int c = lane + k * 64;
    const float ew = enc_w[c];
    a1 += out1w[b * CH + c] * ew;
    const float* o2 = out2w + ((size_t)(b * CH + c)) * NP;
    const float* o3 = out3raw + ((size_t)(b * CH + c)) * NP;
#pragma unroll
    for (int p = 0; p < NP; ++p) { a2[p] += o2[p] * ew; a3[p] += o3[p] * ew; }
  }
#pragma unroll
  for (int st = 32; st >= 1; st >>= 1) {
    a1 += __shfl_xor(a1, st);
#pragma unroll
    for (int p = 0; p < NP; ++p) { a2[p] += __shfl_xor(a2[p], st); a3[p] += __shfl_xor(a3[p], st); }
  }
  __shared__ float proj[30];
  __shared__ float indv[90];
  if (lane == 0) {
#pragma unroll
    for (int p = 0; p < NP; ++p) {
      proj[p] = a1;
      proj[10 + p] = a2[p];
      proj[20 + p] = a3[p] / rowsumg[b * 16 + p];
    }
  }
  __syncthreads();
  if (lane < 30) {
    const float pj = proj[lane];
    const float eb = enc_b[0];
    float lg[30];
    float mx = -1e30f;
#pragma unroll
    for (int j = 0; j < 30; ++j) { lg[j] = pj * sw[j] + eb; mx = fmaxf(mx, lg[j]); }
    float ssum = 0.f;
#pragma unroll
    for (int j = 0; j < 30; ++j) { lg[j] = expf(lg[j] - mx); ssum += lg[j]; }
    const float inv = 1.f / ssum;
    float m0 = 0.f, m1 = 0.f, m2 = 0.f;
#pragma unroll
    for (int j = 0; j < 30; ++j) {
      const float av = lg[j] * inv;
      attn_out[(size_t)b * 900 + lane * 30 + j] = av;
      if (j < 10) m0 += av; else if (j < 20) m1 += av; else m2 += av;
    }
    indv[lane] = m0 * 0.1f; indv[30 + lane] = m1 * 0.1f; indv[60 + lane] = m2 * 0.1f;
  }
  __syncthreads();
  if (lane == 0) {
    float best = -1e30f; int bi = 0;
    for (int k = 0; k < 90; ++k) { const float v = indv[k]; if (v > best) { best = v; bi = k; } }
    atomicAdd(ind_sum, (float)bi);
  }
}

// ---------------- K7b: ensemble = concat_out @ attn (reads out2 means at DO_ONE) ----------------
__global__ __launch_bounds__(256) void k7b_ens(const float* __restrict__ out1w, const float* __restrict__ out2w,
                                               const float* __restrict__ out3raw, const float* __restrict__ rowsumg,
                                               const float* __restrict__ attn, float* __restrict__ ens) {
  const int b = blockIdx.x, tid = threadIdx.x;
  __shared__ float at[900];
  __shared__ float s0[30];
  __shared__ float irs[NP];
  for (int k = tid; k < 900; k += 256) at[k] = attn[(size_t)b * 900 + k];
  if (tid < NP) irs[tid] = 1.f / rowsumg[b * 16 + tid];
  __syncthreads();
  if (tid < 30) {
    float s = 0.f;
    for (int i = 0; i < 10; ++i) s += at[i * 30 + tid];
    s0[tid] = s;
  }
  __syncthreads();
  const int c = tid;
  const float o1 = out1w[b * CH + c];
  float o2[NP], o3[NP];
  const float* p2 = out2w + ((size_t)(b * CH + c)) * NP;
  const float* p3 = out3raw + ((size_t)(b * CH + c)) * NP;
#pragma unroll
  for (int p = 0; p < NP; ++p) { o2[p] = p2[p]; o3[p] = p3[p] * irs[p]; }
  float* dst = ens + ((size_t)(b * CH + c)) * 30;
#pragma unroll
  for (int j = 0; j < 30; ++j) {
    float acc = o1 * s0[j];
#pragma unroll
    for (int p = 0; p < NP; ++p) acc += o2[p] * at[(10 + p) * 30 + j] + o3[p] * at[(20 + p) * 30 + j];
    dst[j] = acc;
  }
}

// ---------------- K7a: one = selected branch (in-place: DO_ONE already holds out2 means) ----------------
__global__ __launch_bounds__(256) void k7a_one(const float* __restrict__ out1w, const float* __restrict__ out3raw,
                                               const float* __restrict__ rowsumg, const float* __restrict__ indws,
                                               float* __restrict__ oneb, float* __restrict__ op_out) {
  const int b = blockIdx.x, c = threadIdx.x;
  const float ind = indws[0] * (1.f / 64.f);
  const int op = ind < 0.6f ? 0 : (ind < 1.6f ? 1 : 2);
  if (b == 0 && c == 0) op_out[0] = (float)op;
  float* dst = oneb + ((size_t)(b * CH + c)) * NP;
  if (op == 0) {
    const float v = out1w[b * CH + c];
#pragma unroll
    for (int p = 0; p < NP; ++p) dst[p] = v;
  } else if (op == 2) {
    const float* s = out3raw + ((size_t)(b * CH + c)) * NP;
#pragma unroll
    for (int p = 0; p < NP; ++p) dst[p] = s[p] / rowsumg[b * 16 + p];
  }
  // op == 1: DO_ONE already holds out2 means
}

// ---------------- K7c: z1 partial GEMM ----------------
__global__ __launch_bounds__(256) void k7c_z1(const float* __restrict__ one_, const float* __restrict__ w1,
                                              float* __restrict__ z1acc) {
  const int kt = blockIdx.x;
  const int mt = blockIdx.y;
  const int tid = threadIdx.x;
  __shared__ float os[64][65];
  __shared__ float wsl[64][65];
  const int k0 = kt * 64, m0 = mt * 64;
#pragma unroll
  for (int k = 0; k < 4; ++k) {
    int idx = tid + k * 256;
    int r = idx >> 4, q = (idx & 15) * 4;
    float4 v1 = *(const float4*)(one_ + (size_t)r * 2560 + m0 + q);
    os[r][q] = v1.x; os[r][q + 1] = v1.y; os[r][q + 2] = v1.z; os[r][q + 3] = v1.w;
    float4 v2 = *(const float4*)(w1 + (size_t)(k0 + r) * 2560 + m0 + q);
    wsl[r][q] = v2.x; wsl[r][q + 1] = v2.y; wsl[r][q + 2] = v2.z; wsl[r][q + 3] = v2.w;
  }
  __syncthreads();
  const int bg = tid >> 4, kg = tid & 15;
  float acc[4][4];
#pragma unroll
  for (int i = 0; i < 4; ++i)
#pragma unroll
    for (int j = 0; j < 4; ++j) acc[i][j] = 0.f;
  for (int m = 0; m < 64; ++m) {
    float ov[4], wv[4];
#pragma unroll
    for (int i = 0; i < 4; ++i) { ov[i] = os[bg * 4 + i][m]; wv[i] = wsl[kg * 4 + i][m]; }
#pragma unroll
    for (int i = 0; i < 4; ++i)
#pragma unroll
      for (int j = 0; j < 4; ++j) acc[i][j] += ov[i] * wv[j];
  }
#pragma unroll
  for (int i = 0; i < 4; ++i)
#pragma unroll
    for (int j = 0; j < 4; ++j)
      atomicAdd(&z1acc[(size_t)(bg * 4 + i) * 512 + k0 + kg * 4 + j], acc[i][j]);
}

// ---------------- K7d: z2 partial GEMM ----------------
__global__ __launch_bounds__(256) void k7d_z2(const float* __restrict__ z1acc, const float* __restrict__ db1,
                                              const float* __restrict__ w2, float* __restrict__ z2acc) {
  const int kt = blockIdx.x;
  const int mt = blockIdx.y;
  const int tid = threadIdx.x;
  __shared__ float os[64][65];
  __shared__ float wsl[64][65];
  const int k0 = kt * 64, m0 = mt * 64;
#pragma unroll
  for (int k = 0; k < 4; ++k) {
    int idx = tid + k * 256;
    int r = idx >> 4, q = (idx & 15) * 4;
    float4 v1 = *(const float4*)(z1acc + (size_t)r * 512 + m0 + q);
    float4 bv = *(const float4*)(db1 + m0 + q);
    os[r][q] = fmaxf(v1.x + bv.x, 0.f); os[r][q + 1] = fmaxf(v1.y + bv.y, 0.f);
    os[r][q + 2] = fmaxf(v1.z + bv.z, 0.f); os[r][q + 3] = fmaxf(v1.w + bv.w, 0.f);
    float4 v2 = *(const float4*)(w2 + (size_t)(k0 + r) * 512 + m0 + q);
    wsl[r][q] = v2.x; wsl[r][q + 1] = v2.y; wsl[r][q + 2] = v2.z; wsl[r][q + 3] = v2.w;
  }
  __syncthreads();
  const int bg = tid >> 4, kg = tid & 15;
  float acc[4][4];
#pragma unroll
  for (int i = 0; i < 4; ++i)
#pragma unroll
    for (int j = 0; j < 4; ++j) acc[i][j] = 0.f;
  for (int m = 0; m < 64; ++m) {
    float ov[4], wv[4];
#pragma unroll
    for (int i = 0; i < 4; ++i) { ov[i] = os[bg * 4 + i][m]; wv[i] = wsl[kg * 4 + i][m]; }
#pragma unroll
    for (int i = 0; i < 4; ++i)
#pragma unroll
      for (int j = 0; j < 4; ++j) acc[i][j] += ov[i] * wv[j];
  }
#pragma unroll
  for (int i = 0; i < 4; ++i)
#pragma unroll
    for (int j = 0; j < 4; ++j)
      atomicAdd(&z2acc[(size_t)(bg * 4 + i) * 1024 + k0 + kg * 4 + j], acc[i][j]);
}

// ---------------- K7e: out = relu(z2+b2) @ w3^T + b3 ----------------
__global__ __launch_bounds__(64) void k7e_out(const float* __restrict__ z2acc, const float* __restrict__ db2,
                                              const float* __restrict__ w3, const float* __restrict__ db3,
                                              float* __restrict__ outp) {
  const int b = blockIdx.x, lane = threadIdx.x;
  float acc[NP];
#pragma unroll
  for (int n = 0; n < NP; ++n) acc[n] = 0.f;
  for (int j = lane; j < 1024; j += 64) {
    float zv = z2acc[(size_t)b * 1024 + j] + db2[j];
    zv = fmaxf(zv, 0.f);
#pragma unroll
    for (int n = 0; n < NP; ++n) acc[n] += zv * w3[(size_t)n * 1024 + j];
  }
#pragma unroll
  for (int n = 0; n < NP; ++n)
#pragma unroll
    for (int st = 32; st >= 1; st >>= 1) acc[n] += __shfl_xor(acc[n], st);
  if (lane == 0) {
#pragma unroll
    for (int n = 0; n < NP; ++n) outp[b * NP + n] = acc[n] + db3[n];
  }
}

// ---------------- launch ----------------
extern "C" void kernel_launch(void* const* d_in, const int* in_sizes, int n_in,
                              void* d_out, int out_size, void* d_ws, size_t ws_size,
                              hipStream_t stream) {
  (void)in_sizes; (void)n_in; (void)out_size; (void)ws_size;
  const float* x      = (const float*)d_in[0];
  const float* conv_w = (const float*)d_in[1];
  const float* conv_b = (const float*)d_in[2];
  const float* protos = (const float*)d_in[3];
  const float* sw     = (const float*)d_in[4];
  const float* enc_w  = (const float*)d_in[5];
  const float* enc_b  = (const float*)d_in[6];
  const float* dw1    = (const float*)d_in[7];
  const float* db1    = (const float*)d_in[8];
  const float* dw2    = (const float*)d_in[9];
  const float* db2    = (const float*)d_in[10];
  const float* dw3    = (const float*)d_in[11];
  const float* db3    = (const float*)d_in[12];
  float* out = (float*)d_out;
  float* ws  = (float*)d_ws;

  float* D2g     = ws + OFF_D2;
  float* Rfg     = ws + OFF_RF;
  float* Qg      = ws + OFF_Q;
  unsigned* bkey = (unsigned*)(ws + OFF_BK);
  float* z1acc   = ws + OFF_BK;            // aliases bkey (dead after k4)
  float* z2acc   = ws + OFF_BK + 32768;
  float* rowsumg = ws + OFF_RS;
  float* rtotg   = ws + OFF_RT;
  float* out1w   = ws + OFF_O1;
  float* out3raw = ws + OFF_O3;
  float* indws   = ws + OFF_IND;
  float* h       = out + DO_H;
  float* out2w   = out + DO_ONE;           // raw sums -> means -> "one"

  hipMemsetAsync(ws + OFF_BK, 0xFF, (size_t)64 * BKROWS * sizeof(float), stream);   // diag-min keys
  hipMemsetAsync(ws + OFF_RS, 0, (WS_END - OFF_RS) * sizeof(float), stream);        // rowsum/out3/ind
  hipMemsetAsync(out + DO_ONE, 0, (size_t)163840 * sizeof(float), stream);          // out2 raw accum

  k1_conv<<<dim3(16, 4, 64), 256, 0, stream>>>(x, conv_w, conv_b, h, out2w);
  k2_d2<<<dim3(8, 64), 256, 0, stream>>>(h, protos, D2g, bkey);
  k3b_fin<<<64, 256, 0, stream>>>(out2w, out1w, bkey);
  k4_dp<<<64, 64, 0, stream>>>(D2g, (const float*)bkey, Rfg, Qg, rtotg);
  hipMemsetAsync(z1acc, 0, (size_t)98304 * sizeof(float), stream);                  // z1+z2 (bkey dead)
  k5_out3<<<dim3(16, 64), 256, 0, stream>>>(h, Rfg, Qg, rtotg, out3raw, rowsumg);
  k6a_head<<<64, 64, 0, stream>>>(out1w, out2w, out3raw, rowsumg, enc_w, enc_b, sw,
                                  out + DO_ATT, indws);
  k7b_ens<<<64, 256, 0, stream>>>(out1w, out2w, out3raw, rowsumg, out + DO_ATT, out + DO_ENS);
  k7a_one<<<64, 256, 0, stream>>>(out1w, out3raw, rowsumg, indws, out + DO_ONE, out + DO_OP);
  k7c_z1<<<dim3(8, 40), 256, 0, stream>>>(out + DO_ONE, dw1, z1acc);
  k7d_z2<<<dim3(16, 8), 256, 0, stream>>>(z1acc, db1, dw2, z2acc);
  k7e_out<<<64, 64, 0, stream>>>(z2acc, db2, dw3, db3, out + DO_OUT);
}